// Round 6
// baseline (312.718 us; speedup 1.0000x reference)
//
#include <hip/hip_runtime.h>
#include <hip/hip_bf16.h>

// Problem constants
#define N_TOK   16384      // B*T
#define HDIM    2048       // H*d_h
#define NH      16
#define DH      128
#define NPAIRS  120
#define KCHUNKS 8
#define NKT     (N_TOK / 64)            // 256 k-tiles of 64 tokens
#define KT_PER_CHUNK (NKT / KCHUNKS)    // 32 panels per chunk
#define NPHASE  (KT_PER_CHUNK / 2)      // 16 phases of 128 tokens
#define PANEL_BYTES 8192                // 128 d-rows x 64 tokens x 1B (fp8)

// Workspace layout (bytes) — total ~45.6 MB
#define MU_OFF     0u
#define RINV_OFF   8192u
#define PC_OFF     16384u                     // 120*128*128 f32 = 7,864,320 B
#define PSUM_OFF   7880704u                   // 256*2048 f32 = 2 MB
#define PSQ_OFF    9977856u                   // 2 MB
#define XT_OFF     12075008u                  // 2048*16384 fp8 = 33,554,432 B

typedef int   i32x8  __attribute__((ext_vector_type(8)));
typedef float f32x16 __attribute__((ext_vector_type(16)));

// ---------------------------------------------------------------- fp8 e4m3 pack
__device__ __forceinline__ unsigned pk4_fp8(float a, float b, float c, float d) {
    int w = __builtin_amdgcn_cvt_pk_fp8_f32(a, b, 0, false);   // bytes 0,1
    w = __builtin_amdgcn_cvt_pk_fp8_f32(c, d, w, true);        // bytes 2,3
    return (unsigned)w;
}

// ---------------------------------------------------------------- pass 1: fused stats + panelized transpose + fp8
// Panel layout (PLAIN token order): row d, byte t = token t (chunk c = tokens 16c..16c+15).
// Stats: per-block partial sums (no atomics).
__global__ __launch_bounds__(256)
void stats_transpose_kernel(const float* __restrict__ X,
                            float* __restrict__ psum, float* __restrict__ psq,
                            unsigned char* __restrict__ Xt) {
    __shared__ float tile[64][129];               // stride 129
    __shared__ float sred[4][32][8];              // cross-wave stats partials
    const int h  = blockIdx.x;                    // 0..15
    const int by = blockIdx.y;                    // 0..255
    const int n0 = by * 64;
    const int tx = threadIdx.x;
    const int w  = tx >> 6, l = tx & 63;
    const int cq = tx & 31;                       // float4 index within 128-col slice
    const int rq0 = tx >> 5;                      // 0..7

    float4 s  = make_float4(0.f, 0.f, 0.f, 0.f);
    float4 ss = make_float4(0.f, 0.f, 0.f, 0.f);
    #pragma unroll
    for (int it = 0; it < 8; ++it) {
        int r = it * 8 + rq0;
        float4 x = *(const float4*)(X + (size_t)(n0 + r) * HDIM + h * DH + cq * 4);
        s.x += x.x; s.y += x.y; s.z += x.z; s.w += x.w;
        ss.x += x.x * x.x; ss.y += x.y * x.y; ss.z += x.z * x.z; ss.w += x.w * x.w;
        tile[r][cq * 4 + 0] = x.x; tile[r][cq * 4 + 1] = x.y;
        tile[r][cq * 4 + 2] = x.z; tile[r][cq * 4 + 3] = x.w;
    }
    s.x += __shfl_down(s.x, 32);  s.y += __shfl_down(s.y, 32);
    s.z += __shfl_down(s.z, 32);  s.w += __shfl_down(s.w, 32);
    ss.x += __shfl_down(ss.x, 32); ss.y += __shfl_down(ss.y, 32);
    ss.z += __shfl_down(ss.z, 32); ss.w += __shfl_down(ss.w, 32);
    if (l < 32) {
        sred[w][l][0] = s.x;  sred[w][l][1] = s.y;
        sred[w][l][2] = s.z;  sred[w][l][3] = s.w;
        sred[w][l][4] = ss.x; sred[w][l][5] = ss.y;
        sred[w][l][6] = ss.z; sred[w][l][7] = ss.w;
    }
    __syncthreads();
    if (tx < 32) {                                // wave 0: per-block partials, NO atomics
        float a0 = 0.f, a1 = 0.f, a2 = 0.f, a3 = 0.f;
        float b0 = 0.f, b1 = 0.f, b2 = 0.f, b3 = 0.f;
        #pragma unroll
        for (int w2 = 0; w2 < 4; ++w2) {
            a0 += sred[w2][tx][0]; a1 += sred[w2][tx][1];
            a2 += sred[w2][tx][2]; a3 += sred[w2][tx][3];
            b0 += sred[w2][tx][4]; b1 += sred[w2][tx][5];
            b2 += sred[w2][tx][6]; b3 += sred[w2][tx][7];
        }
        size_t o = (size_t)by * HDIM + h * DH + tx * 4;
        *(float4*)(psum + o) = make_float4(a0, a1, a2, a3);
        *(float4*)(psq  + o) = make_float4(b0, b1, b2, b3);
    }
    // transpose write: 512 16B-chunks, plain token order
    unsigned char* panel = Xt + ((size_t)h * NKT + by) * PANEL_BYTES;
    #pragma unroll
    for (int it = 0; it < 2; ++it) {
        int q = it * 256 + tx;
        int d = q >> 2, c = q & 3;
        int t0 = c * 16;
        uint4 pk;
        pk.x = pk4_fp8(tile[t0+ 0][d], tile[t0+ 1][d], tile[t0+ 2][d], tile[t0+ 3][d]);
        pk.y = pk4_fp8(tile[t0+ 4][d], tile[t0+ 5][d], tile[t0+ 6][d], tile[t0+ 7][d]);
        pk.z = pk4_fp8(tile[t0+ 8][d], tile[t0+ 9][d], tile[t0+10][d], tile[t0+11][d]);
        pk.w = pk4_fp8(tile[t0+12][d], tile[t0+13][d], tile[t0+14][d], tile[t0+15][d]);
        *(uint4*)(panel + d * 64 + c * 16) = pk;
    }
}

// ---------------------------------------------------------------- pass 2: reduce partials -> mu / rinv
__global__ void finalize_kernel(const float* __restrict__ psum, const float* __restrict__ psq,
                                float* __restrict__ mu, float* __restrict__ rinv) {
    int c = blockIdx.x * 256 + threadIdx.x;       // grid 8 x 256 = 2048
    float s = 0.f, q = 0.f;
    for (int by = 0; by < 256; ++by) {
        s += psum[(size_t)by * HDIM + c];
        q += psq[(size_t)by * HDIM + c];
    }
    float m = s * (1.f / (float)N_TOK);
    float var = (q - (float)N_TOK * m * m) * (1.f / (float)(N_TOK - 1));
    var = fmaxf(var, 0.f);
    mu[c]   = m;
    rinv[c] = 1.f / (sqrtf(var) + 1e-8f);
}

// ---------------------------------------------------------------- pass 3: pairwise raw Gram via MX fp8 MFMA
__device__ __forceinline__ void gload16(const void* gsrc, void* ldst) {
    __builtin_amdgcn_global_load_lds(
        (const __attribute__((address_space(1))) unsigned int*)gsrc,
        (__attribute__((address_space(3))) unsigned int*)ldst,
        16, 0, 0);
}

__global__ __launch_bounds__(256, 4)
void gram_kernel(const unsigned char* __restrict__ Xt, float* __restrict__ pairC) {
    const int kc = blockIdx.x;                    // K-chunk 0..7 -> XCD kc (linear%8)
    const int p  = blockIdx.y;                    // pair 0..119
    int i = 0, rem = p;
    while (rem >= NH - 1 - i) { rem -= NH - 1 - i; ++i; }
    const int j = i + 1 + rem;

    __shared__ alignas(16) unsigned char ldsA[2 * PANEL_BYTES];   // 16 KB (2 panels/phase)
    __shared__ alignas(16) unsigned char ldsB[2 * PANEL_BYTES];   // 16 KB

    const int tx = threadIdx.x;
    const int w  = tx >> 6, l = tx & 63;
    const int wm = w >> 1, wn = w & 1;            // 2x2 wave grid over 128x128
    const int l31 = l & 31, h = l >> 5;

    // Staging: physical chunk (pnl, r, cp) holds source chunk cp ^ ((r>>1)&3)
    unsigned int goff[4];
    int ldsOff[4];
    #pragma unroll
    for (int s = 0; s < 4; ++s) {
        int cfl = s * 256 + tx;                   // 1024 chunks = 2 panels
        int pnl = cfl >> 9, q = cfl & 511;
        int r = q >> 2, cp = q & 3;
        int csrc = cp ^ ((r >> 1) & 3);
        goff[s]   = (unsigned int)(pnl * PANEL_BYTES + r * 64 + csrc * 16);
        ldsOff[s] = s * 4096 + w * 1024;          // wave-uniform LDS base per issue
    }
    const char* Abase = (const char*)Xt + ((size_t)i * NKT + (size_t)kc * KT_PER_CHUNK) * PANEL_BYTES;
    const char* Bbase = (const char*)Xt + ((size_t)j * NKT + (size_t)kc * KT_PER_CHUNK) * PANEL_BYTES;

    f32x16 acc[2][2];
    #pragma unroll
    for (int mi = 0; mi < 2; ++mi)
        #pragma unroll
        for (int ni = 0; ni < 2; ++ni)
            #pragma unroll
            for (int q = 0; q < 16; ++q)
                acc[mi][ni][q] = 0.f;

    // fragment-read geometry: lane half h needs source chunks {2h, 2h+1};
    // physical cp0 = (2h) ^ G(row), G = bits 1..2 of row = (l31>>1)&3
    const int G = (l31 >> 1) & 3;
    const int cp0 = (2 * h) ^ G;
    const int cp1 = cp0 ^ 1;

    for (int ph = 0; ph < NPHASE; ++ph) {
        const char* pa = Abase + (size_t)ph * (2 * PANEL_BYTES);
        const char* pb = Bbase + (size_t)ph * (2 * PANEL_BYTES);
        #pragma unroll
        for (int s = 0; s < 4; ++s)
            gload16(pa + goff[s], (char*)ldsA + ldsOff[s]);
        #pragma unroll
        for (int s = 0; s < 4; ++s)
            gload16(pb + goff[s], (char*)ldsB + ldsOff[s]);
        __syncthreads();

        #pragma unroll
        for (int sub = 0; sub < 2; ++sub) {       // two 64-token panels per phase
            const int pbase = sub * PANEL_BYTES;
            i32x8 a[2], b[2];
            #pragma unroll
            for (int mi = 0; mi < 2; ++mi) {
                int r = wm * 64 + mi * 32 + l31;
                uint4 lo = *(const uint4*)(ldsA + pbase + r * 64 + cp0 * 16);
                uint4 hi = *(const uint4*)(ldsA + pbase + r * 64 + cp1 * 16);
                a[mi] = (i32x8){(int)lo.x,(int)lo.y,(int)lo.z,(int)lo.w,
                                (int)hi.x,(int)hi.y,(int)hi.z,(int)hi.w};
            }
            #pragma unroll
            for (int ni = 0; ni < 2; ++ni) {
                int r = wn * 64 + ni * 32 + l31;
                uint4 lo = *(const uint4*)(ldsB + pbase + r * 64 + cp0 * 16);
                uint4 hi = *(const uint4*)(ldsB + pbase + r * 64 + cp1 * 16);
                b[ni] = (i32x8){(int)lo.x,(int)lo.y,(int)lo.z,(int)lo.w,
                                (int)hi.x,(int)hi.y,(int)hi.z,(int)hi.w};
            }
            #pragma unroll
            for (int mi = 0; mi < 2; ++mi)
                #pragma unroll
                for (int ni = 0; ni < 2; ++ni)
                    acc[mi][ni] = __builtin_amdgcn_mfma_scale_f32_32x32x64_f8f6f4(
                        a[mi], b[ni], acc[mi][ni],
                        0, 0,            // cbsz=fp8, blgp=fp8
                        0, 127,          // scale A: opsel 0, E8M0 127 = 1.0
                        0, 127);         // scale B
        }
        __syncthreads();
    }

    // Epilogue: C/D 32x32 layout: col=lane&31, row=(q&3)+8*(q>>2)+4*h
    float* pc = pairC + (size_t)p * (DH * DH);
    #pragma unroll
    for (int mi = 0; mi < 2; ++mi)
        #pragma unroll
        for (int ni = 0; ni < 2; ++ni)
            #pragma unroll
            for (int q = 0; q < 16; ++q) {
                int row = wm * 64 + mi * 32 + (q & 3) + 8 * (q >> 2) + 4 * h;  // d
                int col = wn * 64 + ni * 32 + l31;                             // e
                atomicAdd(&pc[row * DH + col], acc[mi][ni][q]);
            }
}

// ---------------------------------------------------------------- pass 4: per-pair loss + final accumulate
__global__ void pair_reduce_kernel(const float* __restrict__ pairC, const float* __restrict__ G,
                                   const float* __restrict__ mu, const float* __restrict__ rinv,
                                   float* __restrict__ out) {
    int p = blockIdx.x;
    int i = 0, rem = p;
    while (rem >= NH - 1 - i) { rem -= NH - 1 - i; ++i; }
    int j = i + 1 + rem;
    __shared__ float smui[DH], smuj[DH], sri[DH], srj[DH];
    if (threadIdx.x < DH) {
        smui[threadIdx.x] = mu[i * DH + threadIdx.x];
        smuj[threadIdx.x] = mu[j * DH + threadIdx.x];
        sri[threadIdx.x]  = rinv[i * DH + threadIdx.x];
        srj[threadIdx.x]  = rinv[j * DH + threadIdx.x];
    }
    __syncthreads();
    const float invN = 1.f / (float)N_TOK;
    const float* pc = pairC + (size_t)p * (DH * DH);
    float s = 0.f;
    for (int idx = threadIdx.x; idx < DH * DH; idx += 256) {
        int d = idx >> 7, e = idx & 127;
        float cn = (pc[idx] * invN - smui[d] * smuj[e]) * sri[d] * srj[e];
        float diff = cn - ((d == e) ? 1.f : 0.f);
        s += diff * diff;
    }
    for (int o = 32; o; o >>= 1) s += __shfl_down(s, o);
    __shared__ float red[4];
    if ((threadIdx.x & 63) == 0) red[threadIdx.x >> 6] = s;
    __syncthreads();
    if (threadIdx.x == 0) {
        float t = red[0] + red[1] + red[2] + red[3];
        float x = -15.99f * (G[i * NH + j] - 0.0f);
        float sp = (x > 20.f) ? x : log1pf(expf(x));
        float wgt = 0.929f + (1.f - 0.929f) * sp;
        atomicAdd(out, wgt * t * (1.f / (float)NPAIRS));
    }
}

// ---------------------------------------------------------------- launcher
extern "C" void kernel_launch(void* const* d_in, const int* in_sizes, int n_in,
                              void* d_out, int out_size, void* d_ws, size_t ws_size,
                              hipStream_t stream) {
    const float* X = (const float*)d_in[0];
    const float* G = (const float*)d_in[1];
    float* out = (float*)d_out;
    char* ws = (char*)d_ws;

    float*         mu    = (float*)(ws + MU_OFF);
    float*         rinv  = (float*)(ws + RINV_OFF);
    float*         pairC = (float*)(ws + PC_OFF);
    float*         psum  = (float*)(ws + PSUM_OFF);
    float*         psq   = (float*)(ws + PSQ_OFF);
    unsigned char* Xt    = (unsigned char*)(ws + XT_OFF);

    hipMemsetAsync(ws + PC_OFF, 0, (size_t)NPAIRS * DH * DH * 4, stream);
    hipMemsetAsync(d_out, 0, 4, stream);

    stats_transpose_kernel<<<dim3(16, 256), 256, 0, stream>>>(X, psum, psq, Xt);
    finalize_kernel<<<8, 256, 0, stream>>>(psum, psq, mu, rinv);
    gram_kernel<<<dim3(KCHUNKS, NPAIRS), 256, 0, stream>>>(Xt, pairC);
    pair_reduce_kernel<<<NPAIRS, 256, 0, stream>>>(pairC, G, mu, rinv, out);
}